// Round 3
// baseline (753.804 us; speedup 1.0000x reference)
//
#include <hip/hip_runtime.h>
#include <hip/hip_bf16.h>

using bf16   = __bf16;
using bf16x8 = __attribute__((ext_vector_type(8))) __bf16;
using bf16x4 = __attribute__((ext_vector_type(4))) __bf16;
using f32x4  = __attribute__((ext_vector_type(4))) float;

#define MFMA16(W, X, C) __builtin_amdgcn_mfma_f32_16x16x32_bf16((W), (X), (C), 0, 0, 0)

static constexpr size_t M_TOT = (size_t)16 * 160 * 160;  // 409600

// Prearranged weight fragment offsets (bf16 elements) inside the weight block.
static constexpr size_t O_CV1  = 0;       // 128x64  -> 8192
static constexpr size_t O_CV2P = 8192;    // 128x64  -> 8192
static constexpr size_t O_M0C1 = 16384;   // 64x64   -> 4096
static constexpr size_t O_M0C2 = 20480;   // 576x64  -> 36864
static constexpr size_t O_M1C1 = 57344;   // 64x64   -> 4096
static constexpr size_t O_M1C2 = 61440;   // 576x64  -> 36864
static constexpr size_t O_CV3  = 98304;   // 64x64   -> 4096
static constexpr size_t O_CV4  = 102400;  // 128x128 -> 16384

__device__ __forceinline__ float hsw(float x) {
    return x * fminf(fmaxf(x + 3.f, 0.f), 6.f) * (1.f / 6.f);
}
__device__ __forceinline__ float lrelu(float x) {
    return x >= 0.f ? x : 0.1f * x;
}
__device__ __forceinline__ bf16x8 zero8() {
    bf16x8 t;
#pragma unroll
    for (int b = 0; b < 8; ++b) t[b] = (bf16)0.f;
    return t;
}
__device__ __forceinline__ f32x4 zero4f() {
    f32x4 t = {0.f, 0.f, 0.f, 0.f};
    return t;
}

// Convert fp32 HWIO weight W[KTOT x COUT] (k = tap*Cin+ci) into bf16 MFMA
// A-operand fragments in global memory.
// frag f = ks*NCT+ct: lane holds out-channel j = ct*16 + (lane&15) (MFMA D-row),
// elements b=0..7 at k = ks*32 + (lane>>4)*8 + b.   [m89/m91-verified mapping]
template <int KTOT, int COUT>
__device__ void prep_w(bf16* __restrict__ dst, const float* __restrict__ W,
                       int gid, int gs) {
    constexpr int NKS = KTOT / 32, NCT = COUT / 16;
    for (int idx = gid; idx < NKS * NCT * 64; idx += gs) {
        int lane = idx & 63;
        int f = idx >> 6;
        int ct = f % NCT, ks = f / NCT;
        int j = ct * 16 + (lane & 15);
        int kb = ks * 32 + ((lane >> 4) << 3);
        bf16x8 t;
#pragma unroll
        for (int b = 0; b < 8; ++b) t[b] = (bf16)W[(size_t)(kb + b) * COUT + j];
        *(bf16x8*)(dst + (size_t)idx * 8) = t;
    }
}

// BN fold: dst[c] = scale, dst[128+c] = shift (each set spans 256 floats)
__device__ void prep_bn(float* __restrict__ dst, const float* __restrict__ p,
                        int C, int off, int n, int gid, int gs) {
    for (int c = gid; c < n; c += gs) {
        float g = p[off + c], b = p[C + off + c];
        float m = p[2 * C + off + c], v = p[3 * C + off + c];
        float s = g * rsqrtf(v + 1e-3f);
        dst[c] = s;
        dst[128 + c] = b - m * s;
    }
}

__global__ __launch_bounds__(256) void k_prep(
    const float* __restrict__ w1, const float* __restrict__ w2p,
    const float* __restrict__ m0c1w, const float* __restrict__ m0c2w,
    const float* __restrict__ m1c1w, const float* __restrict__ m1c2w,
    const float* __restrict__ cv3w, const float* __restrict__ cv4w,
    const float* __restrict__ bn1, const float* __restrict__ bncat,
    const float* __restrict__ m0c1b, const float* __restrict__ m0c2b,
    const float* __restrict__ m1c1b, const float* __restrict__ m1c2b,
    const float* __restrict__ bn4, bf16* __restrict__ wb, float* __restrict__ bnb) {
    int gid = blockIdx.x * 256 + threadIdx.x;
    int gs = gridDim.x * 256;
    prep_w<128, 64>(wb + O_CV1, w1, gid, gs);
    prep_w<128, 64>(wb + O_CV2P, w2p, gid, gs);
    prep_w<64, 64>(wb + O_M0C1, m0c1w, gid, gs);
    prep_w<576, 64>(wb + O_M0C2, m0c2w, gid, gs);
    prep_w<64, 64>(wb + O_M1C1, m1c1w, gid, gs);
    prep_w<576, 64>(wb + O_M1C2, m1c2w, gid, gs);
    prep_w<64, 64>(wb + O_CV3, cv3w, gid, gs);
    prep_w<128, 128>(wb + O_CV4, cv4w, gid, gs);
    prep_bn(bnb + 0 * 256, bn1, 64, 0, 64, gid, gs);     // cv1 BN
    prep_bn(bnb + 1 * 256, bncat, 128, 64, 64, gid, gs); // bn_cat hi (x2 half)
    prep_bn(bnb + 2 * 256, m0c1b, 64, 0, 64, gid, gs);
    prep_bn(bnb + 3 * 256, m0c2b, 64, 0, 64, gid, gs);
    prep_bn(bnb + 4 * 256, m1c1b, 64, 0, 64, gid, gs);
    prep_bn(bnb + 5 * 256, m1c2b, 64, 0, 64, gid, gs);
    prep_bn(bnb + 6 * 256, bncat, 128, 0, 64, gid, gs);  // bn_cat lo (x1 half)
    prep_bn(bnb + 7 * 256, bn4, 128, 0, 128, gid, gs);   // cv4 BN
}

// ---------------- k_head: y = hswish(bn1(x@cv1)); x2 = leaky(bncat_hi(x@cv2p))
__global__ __launch_bounds__(256, 3) void k_head(
    const float* __restrict__ x, const bf16* __restrict__ wa,
    const bf16* __restrict__ wbq, const float* __restrict__ bna,
    const float* __restrict__ bnb, bf16* __restrict__ y, bf16* __restrict__ x2) {
    int tid = threadIdx.x;
    int lane = tid & 63, wid = tid >> 6;
    int lr = lane & 15, lg = lane >> 4;
    int m0 = blockIdx.x * 128 + wid * 32;

    f32x4 accy[2][4], accx[2][4];
#pragma unroll
    for (int rt = 0; rt < 2; ++rt)
#pragma unroll
        for (int ct = 0; ct < 4; ++ct) { accy[rt][ct] = zero4f(); accx[rt][ct] = zero4f(); }

#pragma unroll
    for (int ks = 0; ks < 4; ++ks) {
        bf16x8 xa[2];
#pragma unroll
        for (int rt = 0; rt < 2; ++rt) {
            const float* p = x + (size_t)(m0 + rt * 16 + lr) * 128 + ks * 32 + lg * 8;
            f32x4 v0 = *(const f32x4*)p;
            f32x4 v1 = *(const f32x4*)(p + 4);
            bf16x8 t;
#pragma unroll
            for (int b = 0; b < 4; ++b) { t[b] = (bf16)v0[b]; t[b + 4] = (bf16)v1[b]; }
            xa[rt] = t;
        }
#pragma unroll
        for (int ct = 0; ct < 4; ++ct) {
            bf16x8 fa = *(const bf16x8*)(wa + (size_t)((ks * 4 + ct) * 64 + lane) * 8);
            bf16x8 fb = *(const bf16x8*)(wbq + (size_t)((ks * 4 + ct) * 64 + lane) * 8);
#pragma unroll
            for (int rt = 0; rt < 2; ++rt) {
                accy[rt][ct] = MFMA16(fa, xa[rt], accy[rt][ct]);
                accx[rt][ct] = MFMA16(fb, xa[rt], accx[rt][ct]);
            }
        }
    }
#pragma unroll
    for (int rt = 0; rt < 2; ++rt) {
        size_t r = (size_t)(m0 + rt * 16 + lr);
#pragma unroll
        for (int ct = 0; ct < 4; ++ct) {
            int j0 = ct * 16 + lg * 4;
            f32x4 s4 = *(const f32x4*)(bna + j0), h4 = *(const f32x4*)(bna + 128 + j0);
            f32x4 a = accy[rt][ct];
            bf16x4 oy, ox;
#pragma unroll
            for (int b = 0; b < 4; ++b) oy[b] = (bf16)hsw(a[b] * s4[b] + h4[b]);
            *(bf16x4*)(y + r * 64 + j0) = oy;
            s4 = *(const f32x4*)(bnb + j0);
            h4 = *(const f32x4*)(bnb + 128 + j0);
            a = accx[rt][ct];
#pragma unroll
            for (int b = 0; b < 4; ++b) ox[b] = (bf16)lrelu(a[b] * s4[b] + h4[b]);
            *(bf16x4*)(x2 + r * 64 + j0) = ox;
        }
    }
}

// ---------------- k_cb64: out = hswish(bn(in @ W)), 1x1 64->64
__global__ __launch_bounds__(256, 4) void k_cb64(
    const bf16* __restrict__ in, const bf16* __restrict__ wg,
    const float* __restrict__ bnp, bf16* __restrict__ out) {
    int tid = threadIdx.x;
    int lane = tid & 63, wid = tid >> 6;
    int lr = lane & 15, lg = lane >> 4;
    bf16x8 wf[2][4];
#pragma unroll
    for (int ks = 0; ks < 2; ++ks)
#pragma unroll
        for (int ct = 0; ct < 4; ++ct)
            wf[ks][ct] = *(const bf16x8*)(wg + (size_t)((ks * 4 + ct) * 64 + lane) * 8);

    int m0 = blockIdx.x * 256 + wid * 64;
    f32x4 acc[4][4];
#pragma unroll
    for (int rt = 0; rt < 4; ++rt)
#pragma unroll
        for (int ct = 0; ct < 4; ++ct) acc[rt][ct] = zero4f();

#pragma unroll
    for (int ks = 0; ks < 2; ++ks) {
        bf16x8 xa[4];
#pragma unroll
        for (int rt = 0; rt < 4; ++rt)
            xa[rt] = *(const bf16x8*)(in + (size_t)(m0 + rt * 16 + lr) * 64 + ks * 32 + lg * 8);
#pragma unroll
        for (int ct = 0; ct < 4; ++ct)
#pragma unroll
            for (int rt = 0; rt < 4; ++rt)
                acc[rt][ct] = MFMA16(wf[ks][ct], xa[rt], acc[rt][ct]);
    }
#pragma unroll
    for (int rt = 0; rt < 4; ++rt) {
        size_t r = (size_t)(m0 + rt * 16 + lr);
#pragma unroll
        for (int ct = 0; ct < 4; ++ct) {
            int j0 = ct * 16 + lg * 4;
            f32x4 s4 = *(const f32x4*)(bnp + j0), h4 = *(const f32x4*)(bnp + 128 + j0);
            f32x4 a = acc[rt][ct];
            bf16x4 o;
#pragma unroll
            for (int b = 0; b < 4; ++b) o[b] = (bf16)hsw(a[b] * s4[b] + h4[b]);
            *(bf16x4*)(out + r * 64 + j0) = o;
        }
    }
}

// ---------------- k_c3: y += hswish(bn(conv3x3_same(in, W)))   (in-place residual)
// Weights read directly from prearranged global fragments (L1/L2-resident).
// No LDS, no barrier -> 3 waves/SIMD.
__global__ __launch_bounds__(256, 3) void k_c3(
    const bf16* __restrict__ in, const bf16* __restrict__ wg,
    const float* __restrict__ bnp, bf16* __restrict__ y) {
    int tid = threadIdx.x;
    int lane = tid & 63;
    int lr = lane & 15, lg = lane >> 4;
    int m0 = blockIdx.x * 256 + (tid >> 6) * 64;

    int row[4], wc[4], hr[4];
#pragma unroll
    for (int rt = 0; rt < 4; ++rt) {
        int r = m0 + rt * 16 + lr;
        row[rt] = r;
        int q = r / 160;
        wc[rt] = r - q * 160;
        hr[rt] = q % 160;
    }
    f32x4 acc[4][4];
#pragma unroll
    for (int rt = 0; rt < 4; ++rt)
#pragma unroll
        for (int ct = 0; ct < 4; ++ct) acc[rt][ct] = zero4f();

    const bf16* wl = wg + (size_t)lane * 8;  // lane-local fragment base

#pragma unroll
    for (int tap = 0; tap < 9; ++tap) {
        const int dy = tap / 3 - 1, dx = tap % 3 - 1;
        const int roff = dy * 160 + dx;
#pragma unroll
        for (int ks2 = 0; ks2 < 2; ++ks2) {
            int ks = tap * 2 + ks2;
            bf16x8 xa[4];
#pragma unroll
            for (int rt = 0; rt < 4; ++rt) {
                bool v = ((unsigned)(hr[rt] + dy) < 160u) && ((unsigned)(wc[rt] + dx) < 160u);
                bf16x8 t = zero8();
                if (v)
                    t = *(const bf16x8*)(in + (size_t)(row[rt] + roff) * 64 + ks2 * 32 + lg * 8);
                xa[rt] = t;
            }
            bf16x8 wfr[4];
#pragma unroll
            for (int ct = 0; ct < 4; ++ct)
                wfr[ct] = *(const bf16x8*)(wl + (size_t)((ks * 4 + ct) * 64) * 8);
#pragma unroll
            for (int ct = 0; ct < 4; ++ct)
#pragma unroll
                for (int rt = 0; rt < 4; ++rt)
                    acc[rt][ct] = MFMA16(wfr[ct], xa[rt], acc[rt][ct]);
        }
    }
#pragma unroll
    for (int rt = 0; rt < 4; ++rt) {
        size_t r = (size_t)row[rt];
#pragma unroll
        for (int ct = 0; ct < 4; ++ct) {
            int j0 = ct * 16 + lg * 4;
            f32x4 s4 = *(const f32x4*)(bnp + j0), h4 = *(const f32x4*)(bnp + 128 + j0);
            f32x4 a = acc[rt][ct];
            bf16x4 old = *(const bf16x4*)(y + r * 64 + j0);
            bf16x4 o;
#pragma unroll
            for (int b = 0; b < 4; ++b)
                o[b] = (bf16)((float)old[b] + hsw(a[b] * s4[b] + h4[b]));
            *(bf16x4*)(y + r * 64 + j0) = o;
        }
    }
}

// ---------------- k_tail: out = hswish(bn4( [leaky(bncat_lo(y@cv3)) | x2] @ cv4 ))
__global__ __launch_bounds__(256, 3) void k_tail(
    const bf16* __restrict__ y, const bf16* __restrict__ x2,
    const bf16* __restrict__ w3g, const bf16* __restrict__ w4g,
    const float* __restrict__ bnlo, const float* __restrict__ bn4,
    float* __restrict__ out) {
    __shared__ bf16 tl[4 * 32 * 64];  // per-wave 32x64 bf16 tile, XOR-swizzled
    int tid = threadIdx.x;
    int lane = tid & 63, wid = tid >> 6;
    int lr = lane & 15, lg = lane >> 4;
    int m0 = blockIdx.x * 128 + wid * 32;
    char* tlw = (char*)(tl + (size_t)wid * 32 * 64);

    // GEMM1: x1 = y @ cv3, fold bn_cat[:64] + leaky, stash bf16 tile in LDS
    f32x4 a1[2][4];
#pragma unroll
    for (int rt = 0; rt < 2; ++rt)
#pragma unroll
        for (int ct = 0; ct < 4; ++ct) a1[rt][ct] = zero4f();
#pragma unroll
    for (int ks = 0; ks < 2; ++ks) {
        bf16x8 xa[2];
#pragma unroll
        for (int rt = 0; rt < 2; ++rt)
            xa[rt] = *(const bf16x8*)(y + (size_t)(m0 + rt * 16 + lr) * 64 + ks * 32 + lg * 8);
#pragma unroll
        for (int ct = 0; ct < 4; ++ct) {
            bf16x8 wfr = *(const bf16x8*)(w3g + (size_t)((ks * 4 + ct) * 64 + lane) * 8);
#pragma unroll
            for (int rt = 0; rt < 2; ++rt) a1[rt][ct] = MFMA16(wfr, xa[rt], a1[rt][ct]);
        }
    }
#pragma unroll
    for (int rt = 0; rt < 2; ++rt) {
        int rr = rt * 16 + lr;
#pragma unroll
        for (int ct = 0; ct < 4; ++ct) {
            int j0 = ct * 16 + lg * 4;
            f32x4 s4 = *(const f32x4*)(bnlo + j0), h4 = *(const f32x4*)(bnlo + 128 + j0);
            f32x4 a = a1[rt][ct];
            bf16x4 o;
#pragma unroll
            for (int b = 0; b < 4; ++b) o[b] = (bf16)lrelu(a[b] * s4[b] + h4[b]);
            int byo = (rr * 128 + j0 * 2) ^ ((rr & 7) << 4);
            *(bf16x4*)(tlw + byo) = o;
        }
    }
    // Guarantee cross-lane LDS write->read visibility/ordering.
    __syncthreads();

    // GEMM2: K=128 (k 0..63 from LDS tile, k 64..127 from x2)
    f32x4 a2[2][8];
#pragma unroll
    for (int rt = 0; rt < 2; ++rt)
#pragma unroll
        for (int ct = 0; ct < 8; ++ct) a2[rt][ct] = zero4f();
#pragma unroll
    for (int ks = 0; ks < 4; ++ks) {
        bf16x8 xa[2];
        if (ks < 2) {
#pragma unroll
            for (int rt = 0; rt < 2; ++rt) {
                int rr = rt * 16 + lr;
                int byo = (rr * 128 + (ks * 32 + lg * 8) * 2) ^ ((rr & 7) << 4);
                xa[rt] = *(const bf16x8*)(tlw + byo);
            }
        } else {
#pragma unroll
            for (int rt = 0; rt < 2; ++rt)
                xa[rt] = *(const bf16x8*)(x2 + (size_t)(m0 + rt * 16 + lr) * 64 +
                                          (ks - 2) * 32 + lg * 8);
        }
#pragma unroll
        for (int ct = 0; ct < 8; ++ct) {
            bf16x8 wfr = *(const bf16x8*)(w4g + (size_t)((ks * 8 + ct) * 64 + lane) * 8);
#pragma unroll
            for (int rt = 0; rt < 2; ++rt) a2[rt][ct] = MFMA16(wfr, xa[rt], a2[rt][ct]);
        }
    }
#pragma unroll
    for (int rt = 0; rt < 2; ++rt) {
        size_t r = (size_t)(m0 + rt * 16 + lr);
#pragma unroll
        for (int ct = 0; ct < 8; ++ct) {
            int j0 = ct * 16 + lg * 4;
            f32x4 s4 = *(const f32x4*)(bn4 + j0), h4 = *(const f32x4*)(bn4 + 128 + j0);
            f32x4 a = a2[rt][ct];
            f32x4 o;
#pragma unroll
            for (int b = 0; b < 4; ++b) o[b] = hsw(a[b] * s4[b] + h4[b]);
            *(f32x4*)(out + r * 128 + j0) = o;
        }
    }
}

extern "C" void kernel_launch(void* const* d_in, const int* in_sizes, int n_in,
                              void* d_out, int out_size, void* d_ws, size_t ws_size,
                              hipStream_t stream) {
    const float* x      = (const float*)d_in[0];
    const float* cv1_w  = (const float*)d_in[1];
    const float* cv1_bn = (const float*)d_in[2];
    const float* m0c1w  = (const float*)d_in[3];
    const float* m0c1b  = (const float*)d_in[4];
    const float* m0c2w  = (const float*)d_in[5];
    const float* m0c2b  = (const float*)d_in[6];
    const float* m1c1w  = (const float*)d_in[7];
    const float* m1c1b  = (const float*)d_in[8];
    const float* m1c2w  = (const float*)d_in[9];
    const float* m1c2b  = (const float*)d_in[10];
    const float* cv3_w  = (const float*)d_in[11];
    const float* cv2p_w = (const float*)d_in[12];
    const float* bn_cat = (const float*)d_in[13];
    const float* cv4_w  = (const float*)d_in[14];
    const float* cv4_bn = (const float*)d_in[15];
    float* out = (float*)d_out;

    const size_t M = M_TOT;
    bf16* y  = (bf16*)d_ws;                   // [M,64]
    bf16* x2 = y + M * 64;                    // [M,64]
    bf16* h  = x2 + M * 64;                   // [M,64]
    bf16* wb = h + M * 64;                    // prearranged weight fragments
    float* bnb = (float*)(wb + 120832);       // 8 BN sets x 256 floats (16B aligned)

    dim3 blk(256);
    k_prep<<<dim3(64), blk, 0, stream>>>(cv1_w, cv2p_w, m0c1w, m0c2w, m1c1w, m1c2w,
                                         cv3_w, cv4_w, cv1_bn, bn_cat, m0c1b, m0c2b,
                                         m1c1b, m1c2b, cv4_bn, wb, bnb);
    k_head<<<dim3((int)(M / 128)), blk, 0, stream>>>(
        x, wb + O_CV1, wb + O_CV2P, bnb + 0 * 256, bnb + 1 * 256, y, x2);
    k_cb64<<<dim3((int)(M / 256)), blk, 0, stream>>>(y, wb + O_M0C1, bnb + 2 * 256, h);
    k_c3 <<<dim3((int)(M / 256)), blk, 0, stream>>>(h, wb + O_M0C2, bnb + 3 * 256, y);
    k_cb64<<<dim3((int)(M / 256)), blk, 0, stream>>>(y, wb + O_M1C1, bnb + 4 * 256, h);
    k_c3 <<<dim3((int)(M / 256)), blk, 0, stream>>>(h, wb + O_M1C2, bnb + 5 * 256, y);
    k_tail<<<dim3((int)(M / 128)), blk, 0, stream>>>(
        y, x2, wb + O_CV3, wb + O_CV4, bnb + 6 * 256, bnb + 7 * 256, out);
}

// Round 4
// 736.209 us; speedup vs baseline: 1.0239x; 1.0239x over previous
//
#include <hip/hip_runtime.h>
#include <hip/hip_bf16.h>

using bf16   = __bf16;
using bf16x8 = __attribute__((ext_vector_type(8))) __bf16;
using bf16x4 = __attribute__((ext_vector_type(4))) __bf16;
using f32x4  = __attribute__((ext_vector_type(4))) float;

#define MFMA16(W, X, C) __builtin_amdgcn_mfma_f32_16x16x32_bf16((W), (X), (C), 0, 0, 0)

static constexpr size_t M_TOT = (size_t)16 * 160 * 160;  // 409600

// Prearranged weight fragment offsets (bf16 elements) inside the weight block.
static constexpr size_t O_CV1  = 0;       // 128x64  -> 8192
static constexpr size_t O_CV2P = 8192;    // 128x64  -> 8192
static constexpr size_t O_M0C1 = 16384;   // 64x64   -> 4096
static constexpr size_t O_M0C2 = 20480;   // 576x64  -> 36864
static constexpr size_t O_M1C1 = 57344;   // 64x64   -> 4096
static constexpr size_t O_M1C2 = 61440;   // 576x64  -> 36864
static constexpr size_t O_CV3  = 98304;   // 64x64   -> 4096
static constexpr size_t O_CV4  = 102400;  // 128x128 -> 16384

__device__ __forceinline__ float hsw(float x) {
    return x * fminf(fmaxf(x + 3.f, 0.f), 6.f) * (1.f / 6.f);
}
__device__ __forceinline__ float lrelu(float x) {
    return x >= 0.f ? x : 0.1f * x;
}
__device__ __forceinline__ bf16x8 zero8() {
    bf16x8 t;
#pragma unroll
    for (int b = 0; b < 8; ++b) t[b] = (bf16)0.f;
    return t;
}
__device__ __forceinline__ f32x4 zero4f() {
    f32x4 t = {0.f, 0.f, 0.f, 0.f};
    return t;
}

// Convert fp32 HWIO weight W[KTOT x COUT] (k = tap*Cin+ci) into bf16 MFMA
// A-operand fragments in global memory.
// frag f = ks*NCT+ct: lane holds out-channel j = ct*16 + (lane&15) (MFMA D-row),
// elements b=0..7 at k = ks*32 + (lane>>4)*8 + b.   [m89/m91-verified mapping]
template <int KTOT, int COUT>
__device__ void prep_w(bf16* __restrict__ dst, const float* __restrict__ W,
                       int gid, int gs) {
    constexpr int NKS = KTOT / 32, NCT = COUT / 16;
    for (int idx = gid; idx < NKS * NCT * 64; idx += gs) {
        int lane = idx & 63;
        int f = idx >> 6;
        int ct = f % NCT, ks = f / NCT;
        int j = ct * 16 + (lane & 15);
        int kb = ks * 32 + ((lane >> 4) << 3);
        bf16x8 t;
#pragma unroll
        for (int b = 0; b < 8; ++b) t[b] = (bf16)W[(size_t)(kb + b) * COUT + j];
        *(bf16x8*)(dst + (size_t)idx * 8) = t;
    }
}

// BN fold: dst[c] = scale, dst[128+c] = shift (each set spans 256 floats)
__device__ void prep_bn(float* __restrict__ dst, const float* __restrict__ p,
                        int C, int off, int n, int gid, int gs) {
    for (int c = gid; c < n; c += gs) {
        float g = p[off + c], b = p[C + off + c];
        float m = p[2 * C + off + c], v = p[3 * C + off + c];
        float s = g * rsqrtf(v + 1e-3f);
        dst[c] = s;
        dst[128 + c] = b - m * s;
    }
}

__global__ __launch_bounds__(256) void k_prep(
    const float* __restrict__ w1, const float* __restrict__ w2p,
    const float* __restrict__ m0c1w, const float* __restrict__ m0c2w,
    const float* __restrict__ m1c1w, const float* __restrict__ m1c2w,
    const float* __restrict__ cv3w, const float* __restrict__ cv4w,
    const float* __restrict__ bn1, const float* __restrict__ bncat,
    const float* __restrict__ m0c1b, const float* __restrict__ m0c2b,
    const float* __restrict__ m1c1b, const float* __restrict__ m1c2b,
    const float* __restrict__ bn4, bf16* __restrict__ wb, float* __restrict__ bnb) {
    int gid = blockIdx.x * 256 + threadIdx.x;
    int gs = gridDim.x * 256;
    prep_w<128, 64>(wb + O_CV1, w1, gid, gs);
    prep_w<128, 64>(wb + O_CV2P, w2p, gid, gs);
    prep_w<64, 64>(wb + O_M0C1, m0c1w, gid, gs);
    prep_w<576, 64>(wb + O_M0C2, m0c2w, gid, gs);
    prep_w<64, 64>(wb + O_M1C1, m1c1w, gid, gs);
    prep_w<576, 64>(wb + O_M1C2, m1c2w, gid, gs);
    prep_w<64, 64>(wb + O_CV3, cv3w, gid, gs);
    prep_w<128, 128>(wb + O_CV4, cv4w, gid, gs);
    prep_bn(bnb + 0 * 256, bn1, 64, 0, 64, gid, gs);     // cv1 BN
    prep_bn(bnb + 1 * 256, bncat, 128, 64, 64, gid, gs); // bn_cat hi (x2 half)
    prep_bn(bnb + 2 * 256, m0c1b, 64, 0, 64, gid, gs);
    prep_bn(bnb + 3 * 256, m0c2b, 64, 0, 64, gid, gs);
    prep_bn(bnb + 4 * 256, m1c1b, 64, 0, 64, gid, gs);
    prep_bn(bnb + 5 * 256, m1c2b, 64, 0, 64, gid, gs);
    prep_bn(bnb + 6 * 256, bncat, 128, 0, 64, gid, gs);  // bn_cat lo (x1 half)
    prep_bn(bnb + 7 * 256, bn4, 128, 0, 128, gid, gs);   // cv4 BN
}

// ---------------- k_head: y = hswish(bn1(x@cv1)); x2 = leaky(bncat_hi(x@cv2p))
// Weights staged into LDS with cheap vector copies (pre-converted fragments).
__global__ __launch_bounds__(256, 4) void k_head(
    const float* __restrict__ x, const bf16* __restrict__ wa,
    const bf16* __restrict__ wbq, const float* __restrict__ bna,
    const float* __restrict__ bnb, bf16* __restrict__ y, bf16* __restrict__ x2) {
    __shared__ bf16 wa_l[8192], wb_l[8192];  // 16 KB each
    int tid = threadIdx.x;
    for (int i = tid; i < 1024; i += 256) {
        *(bf16x8*)(wa_l + (size_t)i * 8) = *(const bf16x8*)(wa + (size_t)i * 8);
        *(bf16x8*)(wb_l + (size_t)i * 8) = *(const bf16x8*)(wbq + (size_t)i * 8);
    }
    __syncthreads();
    int lane = tid & 63, wid = tid >> 6;
    int lr = lane & 15, lg = lane >> 4;
    int m0 = blockIdx.x * 128 + wid * 32;

    f32x4 accy[2][4], accx[2][4];
#pragma unroll
    for (int rt = 0; rt < 2; ++rt)
#pragma unroll
        for (int ct = 0; ct < 4; ++ct) { accy[rt][ct] = zero4f(); accx[rt][ct] = zero4f(); }

#pragma unroll
    for (int ks = 0; ks < 4; ++ks) {
        bf16x8 xa[2];
#pragma unroll
        for (int rt = 0; rt < 2; ++rt) {
            const float* p = x + (size_t)(m0 + rt * 16 + lr) * 128 + ks * 32 + lg * 8;
            f32x4 v0 = *(const f32x4*)p;
            f32x4 v1 = *(const f32x4*)(p + 4);
            bf16x8 t;
#pragma unroll
            for (int b = 0; b < 4; ++b) { t[b] = (bf16)v0[b]; t[b + 4] = (bf16)v1[b]; }
            xa[rt] = t;
        }
#pragma unroll
        for (int ct = 0; ct < 4; ++ct) {
            bf16x8 fa = *(const bf16x8*)(wa_l + (size_t)((ks * 4 + ct) * 64 + lane) * 8);
            bf16x8 fb = *(const bf16x8*)(wb_l + (size_t)((ks * 4 + ct) * 64 + lane) * 8);
#pragma unroll
            for (int rt = 0; rt < 2; ++rt) {
                accy[rt][ct] = MFMA16(fa, xa[rt], accy[rt][ct]);
                accx[rt][ct] = MFMA16(fb, xa[rt], accx[rt][ct]);
            }
        }
    }
#pragma unroll
    for (int rt = 0; rt < 2; ++rt) {
        size_t r = (size_t)(m0 + rt * 16 + lr);
#pragma unroll
        for (int ct = 0; ct < 4; ++ct) {
            int j0 = ct * 16 + lg * 4;
            f32x4 s4 = *(const f32x4*)(bna + j0), h4 = *(const f32x4*)(bna + 128 + j0);
            f32x4 a = accy[rt][ct];
            bf16x4 oy, ox;
#pragma unroll
            for (int b = 0; b < 4; ++b) oy[b] = (bf16)hsw(a[b] * s4[b] + h4[b]);
            *(bf16x4*)(y + r * 64 + j0) = oy;
            s4 = *(const f32x4*)(bnb + j0);
            h4 = *(const f32x4*)(bnb + 128 + j0);
            a = accx[rt][ct];
#pragma unroll
            for (int b = 0; b < 4; ++b) ox[b] = (bf16)lrelu(a[b] * s4[b] + h4[b]);
            *(bf16x4*)(x2 + r * 64 + j0) = ox;
        }
    }
}

// ---------------- k_cb64: out = hswish(bn(in @ W)), 1x1 64->64  (weights in regs)
__global__ __launch_bounds__(256, 4) void k_cb64(
    const bf16* __restrict__ in, const bf16* __restrict__ wg,
    const float* __restrict__ bnp, bf16* __restrict__ out) {
    int tid = threadIdx.x;
    int lane = tid & 63, wid = tid >> 6;
    int lr = lane & 15, lg = lane >> 4;
    bf16x8 wf[2][4];
#pragma unroll
    for (int ks = 0; ks < 2; ++ks)
#pragma unroll
        for (int ct = 0; ct < 4; ++ct)
            wf[ks][ct] = *(const bf16x8*)(wg + (size_t)((ks * 4 + ct) * 64 + lane) * 8);

    int m0 = blockIdx.x * 256 + wid * 64;
    f32x4 acc[4][4];
#pragma unroll
    for (int rt = 0; rt < 4; ++rt)
#pragma unroll
        for (int ct = 0; ct < 4; ++ct) acc[rt][ct] = zero4f();

#pragma unroll
    for (int ks = 0; ks < 2; ++ks) {
        bf16x8 xa[4];
#pragma unroll
        for (int rt = 0; rt < 4; ++rt)
            xa[rt] = *(const bf16x8*)(in + (size_t)(m0 + rt * 16 + lr) * 64 + ks * 32 + lg * 8);
#pragma unroll
        for (int ct = 0; ct < 4; ++ct)
#pragma unroll
            for (int rt = 0; rt < 4; ++rt)
                acc[rt][ct] = MFMA16(wf[ks][ct], xa[rt], acc[rt][ct]);
    }
#pragma unroll
    for (int rt = 0; rt < 4; ++rt) {
        size_t r = (size_t)(m0 + rt * 16 + lr);
#pragma unroll
        for (int ct = 0; ct < 4; ++ct) {
            int j0 = ct * 16 + lg * 4;
            f32x4 s4 = *(const f32x4*)(bnp + j0), h4 = *(const f32x4*)(bnp + 128 + j0);
            f32x4 a = acc[rt][ct];
            bf16x4 o;
#pragma unroll
            for (int b = 0; b < 4; ++b) o[b] = (bf16)hsw(a[b] * s4[b] + h4[b]);
            *(bf16x4*)(out + r * 64 + j0) = o;
        }
    }
}

// ---------------- k_c3: y += hswish(bn(conv3x3_same(in, W)))   (in-place residual)
// Input band (tile rows + halo = 578 rows x 64ch bf16 = 74 KB) staged in LDS,
// XOR-swizzled on the 16B-column index so stride-128B row reads are
// conflict-free. Weights direct from L2 (uniform per lane across waves).
__global__ __launch_bounds__(256, 2) void k_c3(
    const bf16* __restrict__ in, const bf16* __restrict__ wg,
    const float* __restrict__ bnp, bf16* __restrict__ y) {
    constexpr int NR = 578;              // 256 tile rows + 2*161 halo
    __shared__ bf16 tile[NR * 64];       // 73,984 B
    int tid = threadIdx.x;
    const long g0 = (long)blockIdx.x * 256 - 161;  // first staged flat row
    const char* inb = (const char*)in;

    // Stage: LDS[row][c] = G[row][c ^ (row&7)]  (involutive 16B-col swizzle)
    for (int i = tid; i < NR * 8; i += 256) {
        int row_l = i >> 3, c = i & 7;
        bf16x8 v = *(const bf16x8*)(inb + (g0 + row_l) * 128 + ((c ^ (row_l & 7)) << 4));
        *(bf16x8*)((char*)tile + (size_t)i * 16) = v;
    }
    __syncthreads();

    int lane = tid & 63, wid = tid >> 6;
    int lr = lane & 15, lg = lane >> 4;
    int m0 = blockIdx.x * 256 + wid * 64;

    int row[4], wc[4], hr[4], lbase[4];
#pragma unroll
    for (int rt = 0; rt < 4; ++rt) {
        int r = m0 + rt * 16 + lr;
        row[rt] = r;
        int q = r / 160;
        wc[rt] = r - q * 160;
        hr[rt] = q % 160;
        lbase[rt] = wid * 64 + rt * 16 + lr + 161;  // local row in tile
    }
    f32x4 acc[4][4];
#pragma unroll
    for (int rt = 0; rt < 4; ++rt)
#pragma unroll
        for (int ct = 0; ct < 4; ++ct) acc[rt][ct] = zero4f();

    const bf16* wl = wg + (size_t)lane * 8;  // lane-local fragment base

#pragma unroll
    for (int tap = 0; tap < 9; ++tap) {
        const int dy = tap / 3 - 1, dx = tap % 3 - 1;
        const int roff = dy * 160 + dx;
#pragma unroll
        for (int ks2 = 0; ks2 < 2; ++ks2) {
            int ks = tap * 2 + ks2;
            bf16x8 xa[4];
#pragma unroll
            for (int rt = 0; rt < 4; ++rt) {
                int row_l = lbase[rt] + roff;
                bf16x8 t = *(const bf16x8*)((const char*)tile + (size_t)row_l * 128 +
                                            ((((ks2 << 2) | lg) ^ (row_l & 7)) << 4));
                bool v = ((unsigned)(hr[rt] + dy) < 160u) && ((unsigned)(wc[rt] + dx) < 160u);
                xa[rt] = v ? t : zero8();
            }
            bf16x8 wfr[4];
#pragma unroll
            for (int ct = 0; ct < 4; ++ct)
                wfr[ct] = *(const bf16x8*)(wl + (size_t)((ks * 4 + ct) * 64) * 8);
#pragma unroll
            for (int ct = 0; ct < 4; ++ct)
#pragma unroll
                for (int rt = 0; rt < 4; ++rt)
                    acc[rt][ct] = MFMA16(wfr[ct], xa[rt], acc[rt][ct]);
        }
    }
#pragma unroll
    for (int rt = 0; rt < 4; ++rt) {
        size_t r = (size_t)row[rt];
#pragma unroll
        for (int ct = 0; ct < 4; ++ct) {
            int j0 = ct * 16 + lg * 4;
            f32x4 s4 = *(const f32x4*)(bnp + j0), h4 = *(const f32x4*)(bnp + 128 + j0);
            f32x4 a = acc[rt][ct];
            bf16x4 old = *(const bf16x4*)(y + r * 64 + j0);
            bf16x4 o;
#pragma unroll
            for (int b = 0; b < 4; ++b)
                o[b] = (bf16)((float)old[b] + hsw(a[b] * s4[b] + h4[b]));
            *(bf16x4*)(y + r * 64 + j0) = o;
        }
    }
}

// ---------------- k_tail: out = hswish(bn4( [leaky(bncat_lo(y@cv3)) | x2] @ cv4 ))
__global__ __launch_bounds__(256, 3) void k_tail(
    const bf16* __restrict__ y, const bf16* __restrict__ x2,
    const bf16* __restrict__ w3g, const bf16* __restrict__ w4g,
    const float* __restrict__ bnlo, const float* __restrict__ bn4,
    float* __restrict__ out) {
    __shared__ bf16 w3l[4096];        // 8 KB
    __shared__ bf16 w4l[16384];       // 32 KB
    __shared__ bf16 tl[4 * 32 * 64];  // per-wave 32x64 bf16 tile, XOR-swizzled
    int tid = threadIdx.x;
    for (int i = tid; i < 512; i += 256)
        *(bf16x8*)(w3l + (size_t)i * 8) = *(const bf16x8*)(w3g + (size_t)i * 8);
    for (int i = tid; i < 2048; i += 256)
        *(bf16x8*)(w4l + (size_t)i * 8) = *(const bf16x8*)(w4g + (size_t)i * 8);
    __syncthreads();
    int lane = tid & 63, wid = tid >> 6;
    int lr = lane & 15, lg = lane >> 4;
    int m0 = blockIdx.x * 128 + wid * 32;
    char* tlw = (char*)(tl + (size_t)wid * 32 * 64);

    // GEMM1: x1 = y @ cv3, fold bn_cat[:64] + leaky, stash bf16 tile in LDS
    f32x4 a1[2][4];
#pragma unroll
    for (int rt = 0; rt < 2; ++rt)
#pragma unroll
        for (int ct = 0; ct < 4; ++ct) a1[rt][ct] = zero4f();
#pragma unroll
    for (int ks = 0; ks < 2; ++ks) {
        bf16x8 xa[2];
#pragma unroll
        for (int rt = 0; rt < 2; ++rt)
            xa[rt] = *(const bf16x8*)(y + (size_t)(m0 + rt * 16 + lr) * 64 + ks * 32 + lg * 8);
#pragma unroll
        for (int ct = 0; ct < 4; ++ct) {
            bf16x8 wfr = *(const bf16x8*)(w3l + (size_t)((ks * 4 + ct) * 64 + lane) * 8);
#pragma unroll
            for (int rt = 0; rt < 2; ++rt) a1[rt][ct] = MFMA16(wfr, xa[rt], a1[rt][ct]);
        }
    }
#pragma unroll
    for (int rt = 0; rt < 2; ++rt) {
        int rr = rt * 16 + lr;
#pragma unroll
        for (int ct = 0; ct < 4; ++ct) {
            int j0 = ct * 16 + lg * 4;
            f32x4 s4 = *(const f32x4*)(bnlo + j0), h4 = *(const f32x4*)(bnlo + 128 + j0);
            f32x4 a = a1[rt][ct];
            bf16x4 o;
#pragma unroll
            for (int b = 0; b < 4; ++b) o[b] = (bf16)lrelu(a[b] * s4[b] + h4[b]);
            int byo = (rr * 128 + j0 * 2) ^ ((rr & 7) << 4);
            *(bf16x4*)(tlw + byo) = o;
        }
    }
    // Guarantee cross-lane LDS write->read visibility/ordering.
    __syncthreads();

    // GEMM2: K=128 (k 0..63 from LDS tile, k 64..127 from x2)
    f32x4 a2[2][8];
#pragma unroll
    for (int rt = 0; rt < 2; ++rt)
#pragma unroll
        for (int ct = 0; ct < 8; ++ct) a2[rt][ct] = zero4f();
#pragma unroll
    for (int ks = 0; ks < 4; ++ks) {
        bf16x8 xa[2];
        if (ks < 2) {
#pragma unroll
            for (int rt = 0; rt < 2; ++rt) {
                int rr = rt * 16 + lr;
                int byo = (rr * 128 + (ks * 32 + lg * 8) * 2) ^ ((rr & 7) << 4);
                xa[rt] = *(const bf16x8*)(tlw + byo);
            }
        } else {
#pragma unroll
            for (int rt = 0; rt < 2; ++rt)
                xa[rt] = *(const bf16x8*)(x2 + (size_t)(m0 + rt * 16 + lr) * 64 +
                                          (ks - 2) * 32 + lg * 8);
        }
#pragma unroll
        for (int ct = 0; ct < 8; ++ct) {
            bf16x8 wfr = *(const bf16x8*)(w4l + (size_t)((ks * 8 + ct) * 64 + lane) * 8);
#pragma unroll
            for (int rt = 0; rt < 2; ++rt) a2[rt][ct] = MFMA16(wfr, xa[rt], a2[rt][ct]);
        }
    }
#pragma unroll
    for (int rt = 0; rt < 2; ++rt) {
        size_t r = (size_t)(m0 + rt * 16 + lr);
#pragma unroll
        for (int ct = 0; ct < 8; ++ct) {
            int j0 = ct * 16 + lg * 4;
            f32x4 s4 = *(const f32x4*)(bn4 + j0), h4 = *(const f32x4*)(bn4 + 128 + j0);
            f32x4 a = a2[rt][ct];
            f32x4 o;
#pragma unroll
            for (int b = 0; b < 4; ++b) o[b] = hsw(a[b] * s4[b] + h4[b]);
            *(f32x4*)(out + r * 128 + j0) = o;
        }
    }
}

extern "C" void kernel_launch(void* const* d_in, const int* in_sizes, int n_in,
                              void* d_out, int out_size, void* d_ws, size_t ws_size,
                              hipStream_t stream) {
    const float* x      = (const float*)d_in[0];
    const float* cv1_w  = (const float*)d_in[1];
    const float* cv1_bn = (const float*)d_in[2];
    const float* m0c1w  = (const float*)d_in[3];
    const float* m0c1b  = (const float*)d_in[4];
    const float* m0c2w  = (const float*)d_in[5];
    const float* m0c2b  = (const float*)d_in[6];
    const float* m1c1w  = (const float*)d_in[7];
    const float* m1c1b  = (const float*)d_in[8];
    const float* m1c2w  = (const float*)d_in[9];
    const float* m1c2b  = (const float*)d_in[10];
    const float* cv3_w  = (const float*)d_in[11];
    const float* cv2p_w = (const float*)d_in[12];
    const float* bn_cat = (const float*)d_in[13];
    const float* cv4_w  = (const float*)d_in[14];
    const float* cv4_bn = (const float*)d_in[15];
    float* out = (float*)d_out;

    const size_t M = M_TOT;
    bf16* y  = (bf16*)d_ws;                   // [M,64]
    bf16* x2 = y + M * 64;                    // [M,64]
    bf16* h  = x2 + M * 64;                   // [M,64]
    bf16* wb = h + M * 64;                    // prearranged weight fragments
    float* bnb = (float*)(wb + 120832);       // 8 BN sets x 256 floats (16B aligned)

    dim3 blk(256);
    k_prep<<<dim3(64), blk, 0, stream>>>(cv1_w, cv2p_w, m0c1w, m0c2w, m1c1w, m1c2w,
                                         cv3_w, cv4_w, cv1_bn, bn_cat, m0c1b, m0c2b,
                                         m1c1b, m1c2b, cv4_bn, wb, bnb);
    k_head<<<dim3((int)(M / 128)), blk, 0, stream>>>(
        x, wb + O_CV1, wb + O_CV2P, bnb + 0 * 256, bnb + 1 * 256, y, x2);
    k_cb64<<<dim3((int)(M / 256)), blk, 0, stream>>>(y, wb + O_M0C1, bnb + 2 * 256, h);
    k_c3 <<<dim3((int)(M / 256)), blk, 0, stream>>>(h, wb + O_M0C2, bnb + 3 * 256, y);
    k_cb64<<<dim3((int)(M / 256)), blk, 0, stream>>>(y, wb + O_M1C1, bnb + 4 * 256, h);
    k_c3 <<<dim3((int)(M / 256)), blk, 0, stream>>>(h, wb + O_M1C2, bnb + 5 * 256, y);
    k_tail<<<dim3((int)(M / 128)), blk, 0, stream>>>(
        y, x2, wb + O_CV3, wb + O_CV4, bnb + 6 * 256, bnb + 7 * 256, out);
}